// Round 1
// baseline (449.102 us; speedup 1.0000x reference)
//
#include <hip/hip_runtime.h>

// Problem constants (match reference setup_inputs)
#define GH 720
#define GW 1280
#define GT 20
#define GB 8
#define NEV 500000

__global__ __launch_bounds__(256) void ev2voxel_scatter(
    const float4* __restrict__ ev,      // (B*N) events, each {x, y, t, p}
    const int* __restrict__ counts,     // (B,) valid event counts
    float* __restrict__ out)            // (B, T, H, W) fp32, pre-zeroed
{
    int i = blockIdx.x * blockDim.x + threadIdx.x;
    const int total = GB * NEV;
    if (i >= total) return;

    int b = i / NEV;                    // constant divisor -> magic-mul
    int n = i - b * NEV;
    if (n >= counts[b]) return;

    float4 e = ev[i];

    int x = (int)e.x;
    int y = (int)e.y;
    x = min(max(x, 0), GW - 1);
    y = min(max(y, 0), GH - 1);

    float pol = e.w * 2.0f - 1.0f;      // {0,1} -> {-1,+1}

    float tb = e.z * (float)(GT - 1);   // continuous bin coord in [0, T-1]
    int k0 = (int)floorf(tb);
    float w1 = tb - (float)k0;
    float w0 = 1.0f - w1;
    int k0c = min(max(k0, 0), GT - 1);
    int k1c = min(max(k0 + 1, 0), GT - 1);

    // Direct scatter into final (B, T, H, W) layout — no transpose pass.
    int rowbase = (b * GT) * GH;        // (b*T + k)*H later
    int idx0 = ((rowbase + k0c * GH + y)) * GW + x;
    int idx1 = ((rowbase + k1c * GH + y)) * GW + x;

    atomicAdd(&out[idx0], pol * w0);
    atomicAdd(&out[idx1], pol * w1);
}

extern "C" void kernel_launch(void* const* d_in, const int* in_sizes, int n_in,
                              void* d_out, int out_size, void* d_ws, size_t ws_size,
                              hipStream_t stream) {
    const float4* ev = (const float4*)d_in[0];   // (B, N, 4) fp32
    const int* counts = (const int*)d_in[1];     // (B,) int
    float* out = (float*)d_out;                  // (B, T, H, W) fp32

    // Zero the voxel grid every call (harness poisons d_out, never re-zeros).
    hipMemsetAsync(out, 0, (size_t)out_size * sizeof(float), stream);

    const int total = GB * NEV;
    const int block = 256;
    const int grid = (total + block - 1) / block;
    ev2voxel_scatter<<<grid, block, 0, stream>>>(ev, counts, out);
}